// Round 1
// baseline (26684.488 us; speedup 1.0000x reference)
//
#include <hip/hip_runtime.h>
#include <math.h>

// Persistent cooperative 2-layer LSTM, fp32.
// B=64, T=512, D=128, H=512. Grid: 256 WGs x 256 threads, 1 WG/CU.
// WG w: bgrp = w&1 (batches bgrp*32..+32), cgrp = w>>1 (h-cols cgrp*4..+4).
// Thread: b = tid&31 (local batch), slot = tid>>5: cgp = slot&1 (2 cols), kh = slot>>1 (K quarter).
// Pipeline: iteration t computes layer0 step t, layer1 step t-1, y step t-2. 514 iterations.
// ws layout (floats): [0..16): barrier counter; ring0[2][64][512] at 16; ring1[2][64][512] at 16+65536.

#define B64 64
#define TT 512
#define NWG 256

// smem offsets (floats)
#define SM_W0    0        // [4 cl][4 g][640]   = 10240
#define SM_W1    10240    // [4 cl][4 g][1024]  = 16384
#define SM_HT    26624    // float4 [32 k4][33] = 1056 f4 = 4224 fl
#define SM_RED   30848    // [3][2][32][8]      = 1536
#define SM_WLIN  32384    // 512
#define SM_YBUF  32896    // 256
#define SM_TOT   33152    // 132,608 B LDS

__device__ __forceinline__ float fsigmoid(float v){ return 1.f/(1.f+__expf(-v)); }
__device__ __forceinline__ float ftanh(float v){ return 2.f/(1.f+__expf(-2.f*v)) - 1.f; }

__device__ __forceinline__ void gridbar(unsigned* cnt, unsigned target){
  __syncthreads();
  if (threadIdx.x == 0){
    __threadfence();  // release: flush this WG's stores (wb L2 for cross-XCD)
    __hip_atomic_fetch_add(cnt, 1u, __ATOMIC_RELAXED, __HIP_MEMORY_SCOPE_AGENT);
    while (__hip_atomic_load(cnt, __ATOMIC_RELAXED, __HIP_MEMORY_SCOPE_AGENT) < target)
      __builtin_amdgcn_s_sleep(4);
    __threadfence();  // acquire: invalidate L1/L2 so fresh remote data is visible
  }
  __syncthreads();
}

// Gate dot-products for one layer step. KT = number of 128-float K tiles (5 for L0, 8 for L1).
// srcA: h_prev ring (rows of 128 f4, global batch index). srcB: second operand (x_t or out0), strideBf4 per batch row.
template<int KT>
__device__ __forceinline__ void gates_dot(
    float* smem, const float* Wl,
    const float4* __restrict__ srcA, const float4* __restrict__ srcB, int strideBf4,
    int tid, int b, int bgrp, int cgp, int kh, float acc[2][4])
{
  constexpr int K4 = KT*32;     // f4 per W row
  float4* ht4 = (float4*)(smem + SM_HT);
  const float4* W4 = (const float4*)Wl;

  float4 pf[4];
  // prefetch tile 0
  #pragma unroll
  for (int j=0;j<4;j++){
    int fidx = tid + 256*j; int lb = fidx>>5; int k4 = fidx&31;
    int gb = bgrp*32 + lb; int gk4 = k4;   // tile 0 always in srcA range (gk4<128)
    pf[j] = srcA[gb*128 + gk4];
  }

  for (int kt=0; kt<KT; ++kt){
    __syncthreads();                       // previous tile's reads complete
    #pragma unroll
    for (int j=0;j<4;j++){
      int fidx = tid + 256*j; int lb = fidx>>5; int k4 = fidx&31;
      ht4[k4*33 + lb] = pf[j];
    }
    if (kt+1 < KT){                        // prefetch next tile (overlaps compute)
      #pragma unroll
      for (int j=0;j<4;j++){
        int fidx = tid + 256*j; int lb = fidx>>5; int k4 = fidx&31;
        int gb = bgrp*32 + lb; int gk4 = (kt+1)*32 + k4;
        pf[j] = (gk4 < 128) ? srcA[gb*128 + gk4]
                            : srcB[gb*strideBf4 + (gk4-128)];
      }
    }
    __syncthreads();                       // tile visible
    #pragma unroll
    for (int q=0;q<8;q++){
      int k4l = kh*8 + q;
      float4 hv = ht4[k4l*33 + b];
      int kb = kt*32 + k4l;
      #pragma unroll
      for (int j=0;j<2;j++){
        int cl = cgp*2 + j;
        #pragma unroll
        for (int g=0; g<4; ++g){
          float4 wv = W4[(cl*4+g)*K4 + kb];
          acc[j][g] += hv.x*wv.x + hv.y*wv.y + hv.z*wv.z + hv.w*wv.w;
        }
      }
    }
  }
}

__device__ __forceinline__ void reduce_cell(
    float* smem, float acc[2][4], int b, int cgp, int kh,
    int bb, int colbase, float* cr, float* __restrict__ ringw)
{
  float* red = smem + SM_RED;
  if (kh > 0){
    float* dst = red + ((kh-1)*64 + cgp*32 + b)*8;
    #pragma unroll
    for (int j=0;j<2;j++)
      #pragma unroll
      for (int g=0;g<4;g++) dst[j*4+g] = acc[j][g];
  }
  __syncthreads();
  if (kh == 0){
    #pragma unroll
    for (int r=0;r<3;r++){
      float* s = red + (r*64 + cgp*32 + b)*8;
      #pragma unroll
      for (int j=0;j<2;j++)
        #pragma unroll
        for (int g=0;g<4;g++) acc[j][g] += s[j*4+g];
    }
    #pragma unroll
    for (int j=0;j<2;j++){
      float gi = fsigmoid(acc[j][0]);
      float gf = fsigmoid(acc[j][1]);
      float gg = ftanh   (acc[j][2]);
      float go = fsigmoid(acc[j][3]);
      float c = gf*cr[j] + gi*gg;
      cr[j] = c;
      ringw[bb*512 + colbase + cgp*2 + j] = go * ftanh(c);
    }
  }
}

__global__ __launch_bounds__(256, 1) void lstm_pers(
    const float* __restrict__ x,    const float* __restrict__ h0in, const float* __restrict__ c0in,
    const float* __restrict__ wih0, const float* __restrict__ whh0,
    const float* __restrict__ bih0, const float* __restrict__ bhh0,
    const float* __restrict__ wih1, const float* __restrict__ whh1,
    const float* __restrict__ bih1, const float* __restrict__ bhh1,
    const float* __restrict__ wlin, const float* __restrict__ blin,
    float* __restrict__ out, float* ws)
{
  __shared__ __align__(16) float smem[SM_TOT];
  const int tid = threadIdx.x, wg = blockIdx.x;
  const int b    = tid & 31;
  const int slot = tid >> 5;
  const int cgp  = slot & 1;
  const int kh   = slot >> 1;
  const int bgrp = wg & 1;
  const int cgrp = wg >> 1;
  const int colbase = cgrp*4;
  const int bb = bgrp*32 + b;

  float* ring0 = ws + 16;
  float* ring1 = ws + 16 + 65536;
  unsigned* cnt = (unsigned*)ws;

  // ---- load W slices into LDS (once, resident for the whole kernel) ----
  // W row = [W_hh row (512) ; W_ih row (K2)], matching vec = [h_prev ; x-like]
  for (int idx = tid; idx < 10240; idx += 256){
    int cl = idx / 2560; int rem = idx - cl*2560; int g = rem / 640; int k = rem - g*640;
    int r = g*512 + colbase + cl;
    smem[SM_W0 + idx] = (k < 512) ? whh0[r*512 + k] : wih0[r*128 + (k-512)];
  }
  for (int idx = tid; idx < 16384; idx += 256){
    int cl = idx >> 12; int g = (idx >> 10) & 3; int k = idx & 1023;
    int r = g*512 + colbase + cl;
    smem[SM_W1 + idx] = (k < 512) ? whh1[r*512 + k] : wih1[r*512 + (k-512)];
  }
  for (int idx = tid; idx < 512; idx += 256) smem[SM_WLIN + idx] = wlin[idx];

  // ---- per-thread persistent registers ----
  float bias0[2][4], bias1[2][4], c0r[2], c1r[2];
  #pragma unroll
  for (int j=0;j<2;j++){
    int col = colbase + cgp*2 + j;
    #pragma unroll
    for (int g=0;g<4;g++){
      bias0[j][g] = bih0[g*512+col] + bhh0[g*512+col];
      bias1[j][g] = bih1[g*512+col] + bhh1[g*512+col];
    }
    c0r[j] = c0in[          bb*512 + col];
    c1r[j] = c0in[32768   + bb*512 + col];
  }
  float blin_r = blin[0];

  // ---- init h rings from inputs (grid-strided; each thread exactly one element) ----
  {
    int gidx = wg*256 + tid;            // [0, 65536)
    if (gidx < 32768) ring0[32768 + gidx]           = h0in[gidx];
    else              ring1[32768 + (gidx - 32768)] = h0in[gidx];
  }

  unsigned phase = 1;
  gridbar(cnt, phase*NWG);

  // ---- main pipelined loop ----
  for (int t = 0; t <= TT+1; ++t){
    if (t < TT){  // layer 0, step t
      float acc[2][4];
      #pragma unroll
      for (int j=0;j<2;j++)
        #pragma unroll
        for (int g=0;g<4;g++) acc[j][g] = (kh==0) ? bias0[j][g] : 0.f;
      gates_dot<5>(smem, smem + SM_W0,
                   (const float4*)(ring0 + ((t+1)&1)*32768),
                   (const float4*)x + t*32, 16384,
                   tid, b, bgrp, cgp, kh, acc);
      reduce_cell(smem, acc, b, cgp, kh, bb, colbase, c0r, ring0 + (t&1)*32768);
    }
    if (t >= 1 && t <= TT){  // layer 1, step t-1
      float acc[2][4];
      #pragma unroll
      for (int j=0;j<2;j++)
        #pragma unroll
        for (int g=0;g<4;g++) acc[j][g] = (kh==0) ? bias1[j][g] : 0.f;
      gates_dot<8>(smem, smem + SM_W1,
                   (const float4*)(ring1 + (t&1)*32768),
                   (const float4*)(ring0 + ((t+1)&1)*32768), 128,
                   tid, b, bgrp, cgp, kh, acc);
      reduce_cell(smem, acc, b, cgp, kh, bb, colbase, c1r, ring1 + ((t+1)&1)*32768);
    }
    if (t >= 2 && cgrp == 0){  // y, step t-2 (WGs 0 and 1 cover the two batch halves)
      int sy = t - 2;
      int yb = bgrp*32 + (tid & 31);
      const float4* row4 = (const float4*)(ring1 + (t&1)*32768 + yb*512) + (tid>>5)*16;
      const float4* wl4  = (const float4*)(smem + SM_WLIN) + (tid>>5)*16;
      float p = 0.f;
      #pragma unroll
      for (int j=0;j<16;j++){
        float4 v = row4[j]; float4 w = wl4[j];
        p += v.x*w.x + v.y*w.y + v.z*w.z + v.w*w.w;
      }
      smem[SM_YBUF + (tid&31)*8 + (tid>>5)] = p;
      __syncthreads();
      if (tid < 32){
        float s = 0.f;
        #pragma unroll
        for (int k=0;k<8;k++) s += smem[SM_YBUF + tid*8 + k];
        out[(bgrp*32 + tid)*512 + sy] = s + blin_r;
      }
    }
    ++phase;
    gridbar(cnt, phase*NWG);
  }
}

extern "C" void kernel_launch(void* const* d_in, const int* in_sizes, int n_in,
                              void* d_out, int out_size, void* d_ws, size_t ws_size,
                              hipStream_t stream)
{
  (void)in_sizes; (void)n_in; (void)out_size; (void)ws_size;
  const float* x    = (const float*)d_in[0];
  const float* h0   = (const float*)d_in[1];
  const float* c0   = (const float*)d_in[2];
  const float* wih0 = (const float*)d_in[3];
  const float* whh0 = (const float*)d_in[4];
  const float* bih0 = (const float*)d_in[5];
  const float* bhh0 = (const float*)d_in[6];
  const float* wih1 = (const float*)d_in[7];
  const float* whh1 = (const float*)d_in[8];
  const float* bih1 = (const float*)d_in[9];
  const float* bhh1 = (const float*)d_in[10];
  const float* wlin = (const float*)d_in[11];
  const float* blin = (const float*)d_in[12];
  float* outp = (float*)d_out;
  float* wsp  = (float*)d_ws;

  // reset barrier counter (graph-capturable async memset; rings are fully rewritten each launch)
  hipMemsetAsync(d_ws, 0, 64, stream);

  void* args[] = { &x, &h0, &c0, &wih0, &whh0, &bih0, &bhh0,
                   &wih1, &whh1, &bih1, &bhh1, &wlin, &blin, &outp, &wsp };
  hipLaunchCooperativeKernel((const void*)lstm_pers, dim3(NWG), dim3(256), args, 0, stream);
}

// Round 2
// 21946.002 us; speedup vs baseline: 1.2159x; 1.2159x over previous
//
#include <hip/hip_runtime.h>
#include <math.h>

// Persistent cooperative 2-layer LSTM, fp32.
// B=64, T=512, D=128, H=512. Grid: 256 WGs x 256 threads, 1 WG/CU.
// WG w: bgrp = w&1 (batches bgrp*32..+32), cgrp = w>>1 (h-cols cgrp*4..+4).
// Thread: b = tid&31 (local batch), slot = tid>>5: cgp = slot&1 (2 cols), kh = slot>>1 (K quarter).
// Pipeline: iteration t computes layer0 step t, layer1 step t-1, y step t-2. 514 iterations.
//
// Cross-WG protocol (round 2): per-WG arrival flags + single release word, all
// cross-iteration data written with relaxed agent atomics (write-through to the
// L3 coherence point, never dirty in L2), ring reads plain cached loads made
// safe by one agent acquire fence (buffer_inv) per WG per barrier pass.
//
// ws layout: u32 flags[256] at byte 0; u32 rel at byte 1024; floats:
// ring0[2][64][512] at float-offset 2048; ring1 at 2048+65536.

#define B64 64
#define TT 512
#define NWG 256

// smem offsets (floats)
#define SM_W0    0        // [4 cl][4 g][640]   = 10240
#define SM_W1    10240    // [4 cl][4 g][1024]  = 16384
#define SM_HT    26624    // float4 [32 k4][33] = 1056 f4 = 4224 fl
#define SM_RED   30848    // [3][2][32][8]      = 1536
#define SM_WLIN  32384    // 512
#define SM_YBUF  32896    // 256
#define SM_TOT   33152    // 132,608 B LDS

__device__ __forceinline__ float fsigmoid(float v){ return 1.f/(1.f+__expf(-v)); }
__device__ __forceinline__ float ftanh(float v){ return 2.f/(1.f+__expf(-2.f*v)) - 1.f; }

__device__ __forceinline__ void st_agent(float* p, float v){
  __hip_atomic_store(p, v, __ATOMIC_RELAXED, __HIP_MEMORY_SCOPE_AGENT);
}

__device__ __forceinline__ void gridbar(unsigned* flags, volatile unsigned* rel,
                                        int wg, int tid, unsigned phase){
  // release: my stores (sc1, write-through) must be complete before my flag
  asm volatile("s_waitcnt vmcnt(0)" ::: "memory");
  __syncthreads();
  if (tid == 0)
    __hip_atomic_store(&flags[wg], phase, __ATOMIC_RELAXED, __HIP_MEMORY_SCOPE_AGENT);
  if (wg == 0 && tid < 64){
    unsigned* f4 = flags + tid*4;
    for(;;){
      unsigned a = __hip_atomic_load(&f4[0], __ATOMIC_RELAXED, __HIP_MEMORY_SCOPE_AGENT);
      unsigned b = __hip_atomic_load(&f4[1], __ATOMIC_RELAXED, __HIP_MEMORY_SCOPE_AGENT);
      unsigned c = __hip_atomic_load(&f4[2], __ATOMIC_RELAXED, __HIP_MEMORY_SCOPE_AGENT);
      unsigned d = __hip_atomic_load(&f4[3], __ATOMIC_RELAXED, __HIP_MEMORY_SCOPE_AGENT);
      bool ok = (a>=phase)&(b>=phase)&(c>=phase)&(d>=phase);
      if (__all(ok)) break;
      __builtin_amdgcn_s_sleep(1);
    }
    if (tid == 0)
      __hip_atomic_store((unsigned*)rel, phase, __ATOMIC_RELAXED, __HIP_MEMORY_SCOPE_AGENT);
  }
  if (tid == 0){
    while (__hip_atomic_load((unsigned*)rel, __ATOMIC_RELAXED, __HIP_MEMORY_SCOPE_AGENT) < phase)
      __builtin_amdgcn_s_sleep(2);
  }
  __syncthreads();
  // acquire: invalidate stale L1/L2 lines (ring buffers) before cached reads
  __builtin_amdgcn_fence(__ATOMIC_ACQUIRE, "agent");
}

// Gate dot-products for one layer step. KT = number of 128-float K tiles (5 for L0, 8 for L1).
template<int KT>
__device__ __forceinline__ void gates_dot(
    float* smem, const float* Wl,
    const float4* __restrict__ srcA, const float4* __restrict__ srcB, int strideBf4,
    int tid, int b, int bgrp, int cgp, int kh, float acc[2][4])
{
  constexpr int K4 = KT*32;     // f4 per W row
  float4* ht4 = (float4*)(smem + SM_HT);
  const float4* W4 = (const float4*)Wl;

  float4 pf[4];
  #pragma unroll
  for (int j=0;j<4;j++){
    int fidx = tid + 256*j; int lb = fidx>>5; int k4 = fidx&31;
    int gb = bgrp*32 + lb;
    pf[j] = srcA[gb*128 + k4];
  }

  for (int kt=0; kt<KT; ++kt){
    __syncthreads();
    #pragma unroll
    for (int j=0;j<4;j++){
      int fidx = tid + 256*j; int lb = fidx>>5; int k4 = fidx&31;
      ht4[k4*33 + lb] = pf[j];
    }
    if (kt+1 < KT){
      #pragma unroll
      for (int j=0;j<4;j++){
        int fidx = tid + 256*j; int lb = fidx>>5; int k4 = fidx&31;
        int gb = bgrp*32 + lb; int gk4 = (kt+1)*32 + k4;
        pf[j] = (gk4 < 128) ? srcA[gb*128 + gk4]
                            : srcB[gb*strideBf4 + (gk4-128)];
      }
    }
    __syncthreads();
    #pragma unroll
    for (int q=0;q<8;q++){
      int k4l = kh*8 + q;
      float4 hv = ht4[k4l*33 + b];
      int kb = kt*32 + k4l;
      #pragma unroll
      for (int j=0;j<2;j++){
        int cl = cgp*2 + j;
        #pragma unroll
        for (int g=0; g<4; ++g){
          float4 wv = W4[(cl*4+g)*K4 + kb];
          acc[j][g] += hv.x*wv.x + hv.y*wv.y + hv.z*wv.z + hv.w*wv.w;
        }
      }
    }
  }
}

__device__ __forceinline__ void reduce_cell(
    float* smem, float acc[2][4], int b, int cgp, int kh,
    int bb, int colbase, float* cr, float* __restrict__ ringw)
{
  float* red = smem + SM_RED;
  if (kh > 0){
    float* dst = red + ((kh-1)*64 + cgp*32 + b)*8;
    #pragma unroll
    for (int j=0;j<2;j++)
      #pragma unroll
      for (int g=0;g<4;g++) dst[j*4+g] = acc[j][g];
  }
  __syncthreads();
  if (kh == 0){
    #pragma unroll
    for (int r=0;r<3;r++){
      float* s = red + (r*64 + cgp*32 + b)*8;
      #pragma unroll
      for (int j=0;j<2;j++)
        #pragma unroll
        for (int g=0;g<4;g++) acc[j][g] += s[j*4+g];
    }
    #pragma unroll
    for (int j=0;j<2;j++){
      float gi = fsigmoid(acc[j][0]);
      float gf = fsigmoid(acc[j][1]);
      float gg = ftanh   (acc[j][2]);
      float go = fsigmoid(acc[j][3]);
      float c = gf*cr[j] + gi*gg;
      cr[j] = c;
      st_agent(&ringw[bb*512 + colbase + cgp*2 + j], go * ftanh(c));
    }
  }
}

__global__ __launch_bounds__(256, 1) void lstm_pers(
    const float* __restrict__ x,    const float* __restrict__ h0in, const float* __restrict__ c0in,
    const float* __restrict__ wih0, const float* __restrict__ whh0,
    const float* __restrict__ bih0, const float* __restrict__ bhh0,
    const float* __restrict__ wih1, const float* __restrict__ whh1,
    const float* __restrict__ bih1, const float* __restrict__ bhh1,
    const float* __restrict__ wlin, const float* __restrict__ blin,
    float* __restrict__ out, float* ws)
{
  __shared__ __align__(16) float smem[SM_TOT];
  const int tid = threadIdx.x, wg = blockIdx.x;
  const int b    = tid & 31;
  const int slot = tid >> 5;
  const int cgp  = slot & 1;
  const int kh   = slot >> 1;
  const int bgrp = wg & 1;
  const int cgrp = wg >> 1;
  const int colbase = cgrp*4;
  const int bb = bgrp*32 + b;

  unsigned* flags = (unsigned*)ws;          // [256]
  volatile unsigned* rel = ((unsigned*)ws) + 256;
  float* ring0 = ws + 2048;
  float* ring1 = ws + 2048 + 65536;

  // ---- load W slices into LDS (once) ----
  for (int idx = tid; idx < 10240; idx += 256){
    int cl = idx / 2560; int rem = idx - cl*2560; int g = rem / 640; int k = rem - g*640;
    int r = g*512 + colbase + cl;
    smem[SM_W0 + idx] = (k < 512) ? whh0[r*512 + k] : wih0[r*128 + (k-512)];
  }
  for (int idx = tid; idx < 16384; idx += 256){
    int cl = idx >> 12; int g = (idx >> 10) & 3; int k = idx & 1023;
    int r = g*512 + colbase + cl;
    smem[SM_W1 + idx] = (k < 512) ? whh1[r*512 + k] : wih1[r*512 + (k-512)];
  }
  for (int idx = tid; idx < 512; idx += 256) smem[SM_WLIN + idx] = wlin[idx];

  // ---- per-thread persistent registers ----
  float bias0[2][4], bias1[2][4], c0r[2], c1r[2];
  #pragma unroll
  for (int j=0;j<2;j++){
    int col = colbase + cgp*2 + j;
    #pragma unroll
    for (int g=0;g<4;g++){
      bias0[j][g] = bih0[g*512+col] + bhh0[g*512+col];
      bias1[j][g] = bih1[g*512+col] + bhh1[g*512+col];
    }
    c0r[j] = c0in[          bb*512 + col];
    c1r[j] = c0in[32768   + bb*512 + col];
  }
  float blin_r = blin[0];

  // ---- init h rings (agent-scope stores: cross-XCD readers next iter) ----
  {
    int gidx = wg*256 + tid;            // [0, 65536)
    if (gidx < 32768) st_agent(&ring0[32768 + gidx], h0in[gidx]);
    else              st_agent(&ring1[32768 + (gidx - 32768)], h0in[gidx]);
  }

  unsigned phase = 1;
  gridbar(flags, rel, wg, tid, phase);

  // ---- main pipelined loop ----
  for (int t = 0; t <= TT+1; ++t){
    if (t < TT){  // layer 0, step t
      float acc[2][4];
      #pragma unroll
      for (int j=0;j<2;j++)
        #pragma unroll
        for (int g=0;g<4;g++) acc[j][g] = (kh==0) ? bias0[j][g] : 0.f;
      gates_dot<5>(smem, smem + SM_W0,
                   (const float4*)(ring0 + ((t+1)&1)*32768),
                   (const float4*)x + t*32, 16384,
                   tid, b, bgrp, cgp, kh, acc);
      reduce_cell(smem, acc, b, cgp, kh, bb, colbase, c0r, ring0 + (t&1)*32768);
    }
    if (t >= 1 && t <= TT){  // layer 1, step t-1
      float acc[2][4];
      #pragma unroll
      for (int j=0;j<2;j++)
        #pragma unroll
        for (int g=0;g<4;g++) acc[j][g] = (kh==0) ? bias1[j][g] : 0.f;
      gates_dot<8>(smem, smem + SM_W1,
                   (const float4*)(ring1 + (t&1)*32768),
                   (const float4*)(ring0 + ((t+1)&1)*32768), 128,
                   tid, b, bgrp, cgp, kh, acc);
      reduce_cell(smem, acc, b, cgp, kh, bb, colbase, c1r, ring1 + ((t+1)&1)*32768);
    }
    if (t >= 2 && cgrp == 0){  // y, step t-2
      int sy = t - 2;
      int yb = bgrp*32 + (tid & 31);
      const float4* row4 = (const float4*)(ring1 + (t&1)*32768 + yb*512) + (tid>>5)*16;
      const float4* wl4  = (const float4*)(smem + SM_WLIN) + (tid>>5)*16;
      float p = 0.f;
      #pragma unroll
      for (int j=0;j<16;j++){
        float4 v = row4[j]; float4 w = wl4[j];
        p += v.x*w.x + v.y*w.y + v.z*w.z + v.w*w.w;
      }
      smem[SM_YBUF + (tid&31)*8 + (tid>>5)] = p;
      __syncthreads();
      if (tid < 32){
        float s = 0.f;
        #pragma unroll
        for (int k=0;k<8;k++) s += smem[SM_YBUF + tid*8 + k];
        // agent store: keep out-lines out of L2 so per-iter buffer_inv can't drop them
        st_agent(&out[(bgrp*32 + tid)*512 + sy], s + blin_r);
      }
    }
    ++phase;
    gridbar(flags, rel, wg, tid, phase);
  }
}

extern "C" void kernel_launch(void* const* d_in, const int* in_sizes, int n_in,
                              void* d_out, int out_size, void* d_ws, size_t ws_size,
                              hipStream_t stream)
{
  (void)in_sizes; (void)n_in; (void)out_size; (void)ws_size;
  const float* x    = (const float*)d_in[0];
  const float* h0   = (const float*)d_in[1];
  const float* c0   = (const float*)d_in[2];
  const float* wih0 = (const float*)d_in[3];
  const float* whh0 = (const float*)d_in[4];
  const float* bih0 = (const float*)d_in[5];
  const float* bhh0 = (const float*)d_in[6];
  const float* wih1 = (const float*)d_in[7];
  const float* whh1 = (const float*)d_in[8];
  const float* bih1 = (const float*)d_in[9];
  const float* bhh1 = (const float*)d_in[10];
  const float* wlin = (const float*)d_in[11];
  const float* blin = (const float*)d_in[12];
  float* outp = (float*)d_out;
  float* wsp  = (float*)d_ws;

  // zero flags + rel (8 KB header); rings fully rewritten by the kernel
  hipMemsetAsync(d_ws, 0, 8192, stream);

  void* args[] = { &x, &h0, &c0, &wih0, &whh0, &bih0, &bhh0,
                   &wih1, &whh1, &bih1, &bhh1, &wlin, &blin, &outp, &wsp };
  hipLaunchCooperativeKernel((const void*)lstm_pers, dim3(NWG), dim3(256), args, 0, stream);
}